// Round 8
// baseline (240.912 us; speedup 1.0000x reference)
//
#include <hip/hip_runtime.h>

#define Bsz 8
#define Lx 4096
#define DM 64
#define DI 128
#define NS 16
#define RK 4
#define KC 4
#define NC 64
#define CT 64
#define SS 16
#define TRE 16

typedef __attribute__((ext_vector_type(8))) __bf16 bf16x8v;
typedef __attribute__((ext_vector_type(4))) __bf16 bf16x4v;
typedef __attribute__((ext_vector_type(4))) float f32x4;

__device__ __forceinline__ float fsig(float x){ return 1.f/(1.f+__expf(-x)); }
__device__ __forceinline__ float dot4(float4 a, float4 b){
  return fmaf(a.x,b.x, fmaf(a.y,b.y, fmaf(a.z,b.z, a.w*b.w)));
}

// ---------------------------------------------------------------------------
// A1 v7: LN + in_proj MFMA + conv + x_proj split-bf16 MFMA + fused pass1 scan.
// uA: P1-P2: bf16 X[80][128B] swz | P3: z fp32 [64][132] | P4+: bf16 xc hi(0..16K)/lo(16K..32K) + dtl fp32 @f8448
// uB: P1-P2: bf16 W[256][128B] swz | P3: xi fp32 [67][129] | P5+: bf16 xpw hi(0..12K)/lo(12K..24K) + B-stash fp32 @f6400
// ---------------------------------------------------------------------------
__global__ __launch_bounds__(512) void a1_front(
    const float* __restrict__ x, const float* __restrict__ ln_g, const float* __restrict__ ln_b,
    const float* __restrict__ in_w, const float* __restrict__ conv_w, const float* __restrict__ conv_b,
    const float* __restrict__ xp_w, const float* __restrict__ dtp_w, const float* __restrict__ dt_b,
    const float* __restrict__ A_log,
    float* __restrict__ xcg, float* __restrict__ dtg, float* __restrict__ zg,
    float* __restrict__ Bg, float* __restrict__ Cg,
    float* __restrict__ Pm, float* __restrict__ he)
{
  __shared__ float uA[8704];
  __shared__ float uB[8704];
  const int tid = threadIdx.x;
  const int bx = blockIdx.x;
  const int tile = bx & 63;
  const int i = (bx >> 6) & 1;
  const int b = bx >> 7;
  const int l0 = tile * 64;
  const size_t rbase = (size_t)(b*2+i)*Lx + l0;

  // ---- P1: LN -> bf16 X (uA swz) ; W -> bf16 (uB swz, packed 8B stores) ----
  {
    const int wv8 = tid >> 6, lane = tid & 63;
    const float gg = ln_g[lane], bb = ln_b[lane];
    for (int lr = wv8; lr < 80; lr += 8) {
      float v = 0.f;
      int l = l0 - 3 + lr;
      if (lr < 67 && l >= 0) {
        int pl = i ? (Lx-1-l) : l;
        v = x[((size_t)b*Lx + pl)*DM + lane];
        float s = v, s2 = v*v;
        #pragma unroll
        for (int off=32; off; off>>=1){ s += __shfl_xor(s,off); s2 += __shfl_xor(s2,off); }
        float mu = s * (1.f/DM);
        float rs = rsqrtf(s2*(1.f/DM) - mu*mu + 1e-5f);
        v = (v-mu)*rs*gg + bb;
      }
      *(__bf16*)((char*)uA + ((lr*128 + lane*2) ^ ((lr&7)<<4))) = (__bf16)v;
    }
    #pragma unroll
    for (int it=0; it<8; ++it) {
      int g = it*512 + tid;
      int c = g >> 4, q = g & 15;
      float4 w = *(const float4*)(in_w + ((size_t)(i*2*DI) + c)*DM + q*4);
      bf16x4v hv;
      hv[0]=(__bf16)w.x; hv[1]=(__bf16)w.y; hv[2]=(__bf16)w.z; hv[3]=(__bf16)w.w;
      *(bf16x4v*)((char*)uB + ((c*128 + q*8) ^ ((c&7)<<4))) = hv;
    }
  }
  __syncthreads();

  // ---- P2: in_proj via MFMA ----
  const int lane = tid & 63, wv = tid >> 6;
  f32x4 acc[5][2];
  {
    f32x4 z4 = {0.f, 0.f, 0.f, 0.f};
    #pragma unroll
    for (int mt=0; mt<5; ++mt){ acc[mt][0] = z4; acc[mt][1] = z4; }
    bf16x8v bfr[2][2];
    #pragma unroll
    for (int ntl=0; ntl<2; ++ntl)
      #pragma unroll
      for (int kt=0; kt<2; ++kt){
        int c = (wv*2+ntl)*16 + (lane&15);
        int byt = (c*128 + kt*64 + (lane>>4)*16) ^ ((c&7)<<4);
        bfr[ntl][kt] = *(const bf16x8v*)((const char*)uB + byt);
      }
    #pragma unroll
    for (int mt=0; mt<5; ++mt){
      bf16x8v afr[2];
      #pragma unroll
      for (int kt=0; kt<2; ++kt){
        int row = mt*16 + (lane&15);
        int byt = (row*128 + kt*64 + (lane>>4)*16) ^ ((row&7)<<4);
        afr[kt] = *(const bf16x8v*)((const char*)uA + byt);
      }
      #pragma unroll
      for (int ntl=0; ntl<2; ++ntl){
        acc[mt][ntl] = __builtin_amdgcn_mfma_f32_16x16x32_bf16(afr[0], bfr[ntl][0], acc[mt][ntl], 0,0,0);
        acc[mt][ntl] = __builtin_amdgcn_mfma_f32_16x16x32_bf16(afr[1], bfr[ntl][1], acc[mt][ntl], 0,0,0);
      }
    }
  }
  __syncthreads();

  // ---- P3: frag writeout — xi -> uB[67][129], z -> uA[64][132] ----
  if (wv < 4) {
    #pragma unroll
    for (int mt=0; mt<5; ++mt)
      #pragma unroll
      for (int ntl=0; ntl<2; ++ntl)
        #pragma unroll
        for (int r=0; r<4; ++r){
          int m = mt*16 + (lane>>4)*4 + r;
          if (m <= 66) uB[m*129 + (wv*2+ntl)*16 + (lane&15)] = acc[mt][ntl][r];
        }
  } else {
    #pragma unroll
    for (int mt=0; mt<5; ++mt)
      #pragma unroll
      for (int ntl=0; ntl<2; ++ntl)
        #pragma unroll
        for (int r=0; r<4; ++r){
          int m = mt*16 + (lane>>4)*4 + r;
          if (m >= 3 && m <= 66)
            uA[(m-3)*132 + ((wv-4)*2+ntl)*16 + (lane&15)] = acc[mt][ntl][r];
        }
  }
  __syncthreads();

  // ---- P3b: z -> global, coalesced ----
  #pragma unroll
  for (int it=0; it<4; ++it) {
    int f = it*512 + tid;
    int row = f >> 5, c0 = (f & 31) * 4;
    float4 v = *(const float4*)&uA[row*132 + c0];
    *(float4*)&zg[(rbase + row)*DI + c0] = v;
  }
  __syncthreads();

  // ---- P4: causal conv + silu -> xcg fp32 + bf16 hi/lo in uA ----
  {
    const int d = tid & 127, rh = tid >> 7;
    float4 cw = *(const float4*)(conv_w + (size_t)(i*DI + d)*KC);
    const float cb = conv_b[i*DI + d];
    #pragma unroll 4
    for (int rr=0; rr<16; ++rr) {
      int lr = 3 + rh*16 + rr;
      float v0 = uB[(lr-3)*129 + d];
      float v1 = uB[(lr-2)*129 + d];
      float v2 = uB[(lr-1)*129 + d];
      float v3 = uB[(lr  )*129 + d];
      float a = cb + cw.x*v0 + cw.y*v1 + cw.z*v2 + cw.w*v3;
      float xc = a * fsig(a);
      int r = lr - 3;
      xcg[(rbase + r)*DI + d] = xc;
      __bf16 hh = (__bf16)xc;
      __bf16 ll = (__bf16)(xc - (float)hh);
      int off = (r*256 + d*2) ^ ((r&7)<<4);
      *(__bf16*)((char*)uA + off) = hh;
      *(__bf16*)((char*)uA + off + 16384) = ll;
    }
  }
  __syncthreads();

  // ---- P5: stage xp_w hi/lo bf16 into uB (xi dead) ----
  for (int e = tid; e < 36*32; e += 512) {
    int j = e >> 5, k0 = (e & 31)*4;
    float4 w = *(const float4*)(xp_w + ((size_t)(i*36) + j)*DI + k0);
    float vv[4] = {w.x, w.y, w.z, w.w};
    bf16x4v hv, lv;
    #pragma unroll
    for (int k=0;k<4;++k){
      __bf16 hh = (__bf16)vv[k];
      hv[k] = hh;
      lv[k] = (__bf16)(vv[k] - (float)hh);
    }
    int off = (j*256 + k0*2) ^ ((j&7)<<4);
    *(bf16x4v*)((char*)uB + off) = hv;
    *(bf16x4v*)((char*)uB + off + 12288) = lv;
  }
  __syncthreads();

  // ---- P6: x_proj split-precision MFMA; dtl->uA, B->Bg+stash, C->Cg ----
  for (int t = wv; t < 12; t += 8) {
    int mt = t & 3, nt = t >> 2;
    f32x4 a2 = {0.f,0.f,0.f,0.f};
    #pragma unroll
    for (int kt=0; kt<4; ++kt){
      int row = mt*16 + (lane&15);
      int ab = (row*256 + kt*64 + (lane>>4)*16) ^ ((row&7)<<4);
      bf16x8v ah = *(const bf16x8v*)((const char*)uA + ab);
      bf16x8v al = *(const bf16x8v*)((const char*)uA + ab + 16384);
      int col = nt*16 + (lane&15);
      int bby = (col*256 + kt*64 + (lane>>4)*16) ^ ((col&7)<<4);
      bf16x8v bh = *(const bf16x8v*)((const char*)uB + bby);
      bf16x8v bl = *(const bf16x8v*)((const char*)uB + bby + 12288);
      a2 = __builtin_amdgcn_mfma_f32_16x16x32_bf16(ah, bh, a2, 0,0,0);
      a2 = __builtin_amdgcn_mfma_f32_16x16x32_bf16(al, bh, a2, 0,0,0);
      a2 = __builtin_amdgcn_mfma_f32_16x16x32_bf16(ah, bl, a2, 0,0,0);
    }
    #pragma unroll
    for (int rg4=0; rg4<4; ++rg4){
      int row = mt*16 + (lane>>4)*4 + rg4;
      int j = nt*16 + (lane&15);
      float val = a2[rg4];
      if (j < 4) uA[8448 + row*4 + j] = val;
      else if (j < 20) { Bg[(rbase+row)*NS + (j-4)] = val; uB[6400 + row*16 + (j-4)] = val; }
      else if (j < 36) Cg[(rbase+row)*NS + (j-20)] = val;
    }
  }
  __syncthreads();

  // ---- P7: fused pass1 scan (128 threads: one per d, all 16 states) ----
  if (tid < 128) {
    const int d = tid;
    float a[16];
    bool afast = true;
    #pragma unroll
    for (int k=0;k<4;++k){
      float4 al = *(const float4*)(A_log + ((size_t)(i*DI)+d)*NS + k*4);
      float vv[4] = {al.x, al.y, al.z, al.w};
      #pragma unroll
      for (int n=0;n<4;++n){
        a[k*4+n] = -__expf(vv[n]);
        float tgt = (float)(k*4+n+1);
        afast = afast && (fabsf(a[k*4+n] + tgt) <= 1e-4f*tgt);
      }
    }
    float4 w4 = *(const float4*)(dtp_w + (size_t)(i*DI + d)*RK);
    const float bias = dt_b[i*DI + d];
    float h[16];
    #pragma unroll
    for (int n=0;n<16;++n) h[n]=0.f;
    float S = 0.f;
    for (int r=0; r<64; ++r){
      float4 dl = *(const float4*)&uA[8448 + r*4];
      float v = bias + dot4(w4, dl);
      float dtt = (v > 20.f) ? v : log1pf(__expf(v));
      dtg[(rbase + r)*DI + d] = dtt;
      S += dtt;
      int off = (r*256 + d*2) ^ ((r&7)<<4);
      float xch = (float)*(const __bf16*)((const char*)uA + off);
      float xcl = (float)*(const __bf16*)((const char*)uA + off + 16384);
      float u = dtt * (xch + xcl);
      float4 b0 = *(const float4*)&uB[6400 + r*16];
      float4 b1 = *(const float4*)&uB[6400 + r*16 + 4];
      float4 b2 = *(const float4*)&uB[6400 + r*16 + 8];
      float4 b3 = *(const float4*)&uB[6400 + r*16 + 12];
      float bb[16] = {b0.x,b0.y,b0.z,b0.w,b1.x,b1.y,b1.z,b1.w,
                      b2.x,b2.y,b2.z,b2.w,b3.x,b3.y,b3.z,b3.w};
      if (afast){
        float rr = __expf(-dtt);
        float dA = rr;
        h[0] = fmaf(dA, h[0], u*bb[0]);
        #pragma unroll
        for (int n=1;n<16;++n){ dA *= rr; h[n] = fmaf(dA, h[n], u*bb[n]); }
      } else {
        #pragma unroll
        for (int n=0;n<16;++n){
          float dA = __expf(a[n]*dtt);
          h[n] = fmaf(dA, h[n], u*bb[n]);
        }
      }
    }
    size_t ob = (((size_t)(b*2+i)*NC + tile)*DI + d)*NS;
    float p[16];
    if (afast){
      float es = __expf(-S);
      p[0] = es;
      #pragma unroll
      for (int n=1;n<16;++n) p[n] = p[n-1]*es;
    } else {
      #pragma unroll
      for (int n=0;n<16;++n) p[n] = __expf(a[n]*S);
    }
    #pragma unroll
    for (int k=0;k<4;++k){
      *(float4*)&Pm[ob + k*4] = make_float4(p[k*4],p[k*4+1],p[k*4+2],p[k*4+3]);
      *(float4*)&he[ob + k*4] = make_float4(h[k*4],h[k*4+1],h[k*4+2],h[k*4+3]);
    }
  }
}

// ---------------------------------------------------------------------------
// KC: pass2 — propagate chunk boundary states; h0 written IN PLACE over Pm
// ---------------------------------------------------------------------------
__global__ __launch_bounds__(256) void kc_pass2(
    float* __restrict__ Pm, const float* __restrict__ hend)
{
  const int tid = threadIdx.x;
  const int bi = blockIdx.x;
  const int d = tid>>1, n0 = (tid&1)*8;
  float h[8];
  #pragma unroll
  for (int n=0;n<8;++n) h[n]=0.f;
  for (int c=0;c<NC;++c){
    size_t ob = (((size_t)bi*NC + c)*DI + d)*NS + n0;
    float p[8], hev[8];
    #pragma unroll
    for (int n=0;n<8;++n){ p[n]=Pm[ob+n]; hev[n]=hend[ob+n]; }
    #pragma unroll
    for (int n=0;n<8;++n){ Pm[ob+n] = h[n]; h[n] = fmaf(p[n], h[n], hev[n]); }
  }
}

// ---------------------------------------------------------------------------
// KD: pass3 — scan with true h0, y = C.h + D-skip, gate silu(z); y -> dtg
// ---------------------------------------------------------------------------
__global__ __launch_bounds__(256) void kd_pass3(
    const float* dtg, const float* __restrict__ xcg, const float* __restrict__ Bg,
    const float* __restrict__ Cg, const float* __restrict__ A_log, const float* __restrict__ Dp,
    const float* __restrict__ h0, const float* __restrict__ zg, float* yout)
{
  __shared__ float s_dt[SS][DI];
  __shared__ float s_x[SS][DI];
  __shared__ float s_z[SS][DI];
  __shared__ float s_B[SS][NS];
  __shared__ float s_C[SS][NS];
  const int tid = threadIdx.x;
  const int bx = blockIdx.x;
  const int c = bx % NC; const int i = (bx/NC)&1; const int b = bx/(2*NC);
  const int d = tid >> 1, half = tid & 1, n0 = half*8;
  float a[8], h[8];
  bool afast = true;
  size_t hb = (((size_t)(b*2+i)*NC + c)*DI + d)*NS + n0;
  #pragma unroll
  for (int n=0;n<8;++n){
    a[n] = -__expf(A_log[((size_t)(i*DI)+d)*NS + n0+n]);
    float tgt = (float)(n0+n+1);
    afast = afast && (fabsf(a[n] + tgt) <= 1e-4f*tgt);
    h[n] = h0[hb+n];
  }
  const float Dd = Dp[i*DI + d];
  const size_t rb = ((size_t)(b*2+i)*Lx + (size_t)c*CT);
  for (int s=0; s<CT/SS; ++s){
    __syncthreads();
    #pragma unroll
    for (int it=0, e=tid; it<(SS*DI)/256; ++it, e+=256){
      int t = e >> 7, dd = e & (DI-1);
      size_t g = (rb + s*SS + t)*DI + dd;
      s_dt[t][dd] = dtg[g];
      s_x[t][dd]  = xcg[g];
      s_z[t][dd]  = zg[g];
    }
    {
      int t = tid >> 4, nn = tid & (NS-1);
      s_B[t][nn] = Bg[(rb + s*SS + t)*NS + nn];
      s_C[t][nn] = Cg[(rb + s*SS + t)*NS + nn];
    }
    __syncthreads();
    #pragma unroll
    for (int t=0;t<SS;++t){
      float dtt = s_dt[t][d];
      float xcv = s_x[t][d];
      float u = dtt * xcv;
      float4 b0 = *(const float4*)(&s_B[t][n0]);
      float4 b1 = *(const float4*)(&s_B[t][n0+4]);
      float4 c0 = *(const float4*)(&s_C[t][n0]);
      float4 c1 = *(const float4*)(&s_C[t][n0+4]);
      float bb[8] = {b0.x,b0.y,b0.z,b0.w,b1.x,b1.y,b1.z,b1.w};
      float cc[8] = {c0.x,c0.y,c0.z,c0.w,c1.x,c1.y,c1.z,c1.w};
      float part = 0.f;
      if (afast){
        float rr = __expf(-dtt);
        float dA;
        if (half){ float r2=rr*rr, r4=r2*r2; dA = r4*r4*rr; } else dA = rr;
        h[0] = fmaf(dA, h[0], u*bb[0]);
        part = fmaf(h[0], cc[0], part);
        #pragma unroll
        for (int n=1;n<8;++n){
          dA *= rr;
          h[n] = fmaf(dA, h[n], u*bb[n]);
          part = fmaf(h[n], cc[n], part);
        }
      } else {
        #pragma unroll
        for (int n=0;n<8;++n){
          float dA = __expf(a[n]*dtt);
          h[n] = fmaf(dA, h[n], u*bb[n]);
          part = fmaf(h[n], cc[n], part);
        }
      }
      float y = part + __shfl_xor(part, 1);
      if (half == 0){
        float zz = s_z[t][d];
        yout[(rb + s*SS + t)*DI + d] = fmaf(xcv, Dd, y) * (zz * fsig(zz));
      }
    }
  }
}

// ---------------------------------------------------------------------------
// KE: out-proj, sum both directions (dir1 read flipped)
// ---------------------------------------------------------------------------
__global__ __launch_bounds__(256) void ke_out(
    const float* __restrict__ yg, const float* __restrict__ ow, float* __restrict__ out)
{
  __shared__ float s_y0[TRE][DI];
  __shared__ float s_y1[TRE][DI];
  const int tid = threadIdx.x;
  const int bx = blockIdx.x;
  const int ntile = Lx / TRE;
  const int tile = bx % ntile; const int b = bx / ntile;
  const int l0 = tile * TRE;
  #pragma unroll
  for (int it=0, e=tid; it<(TRE*DI)/256; ++it, e+=256){
    int r = e >> 7, dd = e & (DI-1);
    s_y0[r][dd] = yg[((size_t)(b*2+0)*Lx + (size_t)(l0+r))*DI + dd];
    s_y1[r][dd] = yg[((size_t)(b*2+1)*Lx + (size_t)(Lx-1-(l0+r)))*DI + dd];
  }
  __syncthreads();
  const int m = tid & 63, r0 = tid >> 6;
  const float4* w0 = (const float4*)(ow + (size_t)m*DI);
  const float4* w1 = (const float4*)(ow + (size_t)(DM+m)*DI);
  float acc[4] = {0.f,0.f,0.f,0.f};
  #pragma unroll
  for (int k=0;k<DI/4;++k){
    float4 a0 = w0[k], a1 = w1[k];
    #pragma unroll
    for (int j=0;j<4;++j){
      const float4 y0 = *(const float4*)(&s_y0[r0+j*4][k*4]);
      const float4 y1 = *(const float4*)(&s_y1[r0+j*4][k*4]);
      acc[j] += dot4(a0,y0) + dot4(a1,y1);
    }
  }
  #pragma unroll
  for (int j=0;j<4;++j)
    out[((size_t)b*Lx + (size_t)(l0 + r0 + j*4))*DM + m] = acc[j];
}

extern "C" void kernel_launch(void* const* d_in, const int* in_sizes, int n_in,
                              void* d_out, int out_size, void* d_ws, size_t ws_size,
                              hipStream_t stream)
{
  const float* x      = (const float*)d_in[0];
  const float* ln_g   = (const float*)d_in[1];
  const float* ln_b   = (const float*)d_in[2];
  const float* in_w   = (const float*)d_in[3];
  const float* conv_w = (const float*)d_in[4];
  const float* conv_b = (const float*)d_in[5];
  const float* xp_w   = (const float*)d_in[6];
  const float* dtp_w  = (const float*)d_in[7];
  const float* dt_b   = (const float*)d_in[8];
  const float* A_log  = (const float*)d_in[9];
  const float* Dp     = (const float*)d_in[10];
  const float* ow     = (const float*)d_in[11];
  float* out = (float*)d_out;
  float* ws = (float*)d_ws;
  const size_t NBD = (size_t)Bsz*2*Lx*DI;     // 8,388,608
  const size_t NBN = (size_t)Bsz*2*Lx*NS;     // 1,048,576
  float* xcg = ws;
  float* dtg = xcg + NBD;
  float* zg  = dtg + NBD;
  float* Bg  = zg + NBD;
  float* Cg  = Bg + NBN;
  float* Pm  = Cg + NBN;          // Bsz*2*NC*DI*NS = 2,097,152 floats; becomes h0 after kc
  float* he  = out;               // hend staged in d_out (fully overwritten by ke)

  a1_front<<<dim3(Bsz*2*(Lx/64)), dim3(512), 0, stream>>>(
      x, ln_g, ln_b, in_w, conv_w, conv_b, xp_w, dtp_w, dt_b, A_log,
      xcg, dtg, zg, Bg, Cg, Pm, he);
  kc_pass2<<<dim3(Bsz*2), dim3(256), 0, stream>>>(Pm, he);
  kd_pass3<<<dim3(Bsz*2*NC), dim3(256), 0, stream>>>(dtg, xcg, Bg, Cg, A_log, Dp, Pm, zg, dtg);
  ke_out<<<dim3(Bsz*(Lx/TRE)), dim3(256), 0, stream>>>(dtg, ow, out);
}

// Round 9
// 222.545 us; speedup vs baseline: 1.0825x; 1.0825x over previous
//
#include <hip/hip_runtime.h>

#define Bsz 8
#define Lx 4096
#define DM 64
#define DI 128
#define NS 16
#define RK 4
#define KC 4
#define NC 64
#define CT 64
#define TRE 16

typedef __attribute__((ext_vector_type(8))) __bf16 bf16x8v;
typedef __attribute__((ext_vector_type(4))) __bf16 bf16x4v;
typedef __attribute__((ext_vector_type(4))) float f32x4;

__device__ __forceinline__ float fsig(float x){ return 1.f/(1.f+__expf(-x)); }
__device__ __forceinline__ float dot4(float4 a, float4 b){
  return fmaf(a.x,b.x, fmaf(a.y,b.y, fmaf(a.z,b.z, a.w*b.w)));
}

// ---------------------------------------------------------------------------
// A1 v8: LN + in_proj MFMA + conv + x_proj split-bf16 MFMA + dt (all-thread).
// (round-8 fused P1-scan reverted: serial tail on 2 waves cost more than kb)
// ---------------------------------------------------------------------------
__global__ __launch_bounds__(512) void a1_front(
    const float* __restrict__ x, const float* __restrict__ ln_g, const float* __restrict__ ln_b,
    const float* __restrict__ in_w, const float* __restrict__ conv_w, const float* __restrict__ conv_b,
    const float* __restrict__ xp_w, const float* __restrict__ dtp_w, const float* __restrict__ dt_b,
    float* __restrict__ xcg, float* __restrict__ dtg, float* __restrict__ zg,
    float* __restrict__ Bg, float* __restrict__ Cg)
{
  __shared__ float uA[8704];
  __shared__ float uB[8704];
  const int tid = threadIdx.x;
  const int bx = blockIdx.x;
  const int tile = bx & 63;
  const int i = (bx >> 6) & 1;
  const int b = bx >> 7;
  const int l0 = tile * 64;
  const size_t rbase = (size_t)(b*2+i)*Lx + l0;

  // ---- P1: LN -> bf16 X (uA swz) ; W -> bf16 (uB swz, packed 8B stores) ----
  {
    const int wv8 = tid >> 6, lane = tid & 63;
    const float gg = ln_g[lane], bb = ln_b[lane];
    for (int lr = wv8; lr < 80; lr += 8) {
      float v = 0.f;
      int l = l0 - 3 + lr;
      if (lr < 67 && l >= 0) {
        int pl = i ? (Lx-1-l) : l;
        v = x[((size_t)b*Lx + pl)*DM + lane];
        float s = v, s2 = v*v;
        #pragma unroll
        for (int off=32; off; off>>=1){ s += __shfl_xor(s,off); s2 += __shfl_xor(s2,off); }
        float mu = s * (1.f/DM);
        float rs = rsqrtf(s2*(1.f/DM) - mu*mu + 1e-5f);
        v = (v-mu)*rs*gg + bb;
      }
      *(__bf16*)((char*)uA + ((lr*128 + lane*2) ^ ((lr&7)<<4))) = (__bf16)v;
    }
    #pragma unroll
    for (int it=0; it<8; ++it) {
      int g = it*512 + tid;
      int c = g >> 4, q = g & 15;
      float4 w = *(const float4*)(in_w + ((size_t)(i*2*DI) + c)*DM + q*4);
      bf16x4v hv;
      hv[0]=(__bf16)w.x; hv[1]=(__bf16)w.y; hv[2]=(__bf16)w.z; hv[3]=(__bf16)w.w;
      *(bf16x4v*)((char*)uB + ((c*128 + q*8) ^ ((c&7)<<4))) = hv;
    }
  }
  __syncthreads();

  // ---- P2: in_proj via MFMA ----
  const int lane = tid & 63, wv = tid >> 6;
  f32x4 acc[5][2];
  {
    f32x4 z4 = {0.f, 0.f, 0.f, 0.f};
    #pragma unroll
    for (int mt=0; mt<5; ++mt){ acc[mt][0] = z4; acc[mt][1] = z4; }
    bf16x8v bfr[2][2];
    #pragma unroll
    for (int ntl=0; ntl<2; ++ntl)
      #pragma unroll
      for (int kt=0; kt<2; ++kt){
        int c = (wv*2+ntl)*16 + (lane&15);
        int byt = (c*128 + kt*64 + (lane>>4)*16) ^ ((c&7)<<4);
        bfr[ntl][kt] = *(const bf16x8v*)((const char*)uB + byt);
      }
    #pragma unroll
    for (int mt=0; mt<5; ++mt){
      bf16x8v afr[2];
      #pragma unroll
      for (int kt=0; kt<2; ++kt){
        int row = mt*16 + (lane&15);
        int byt = (row*128 + kt*64 + (lane>>4)*16) ^ ((row&7)<<4);
        afr[kt] = *(const bf16x8v*)((const char*)uA + byt);
      }
      #pragma unroll
      for (int ntl=0; ntl<2; ++ntl){
        acc[mt][ntl] = __builtin_amdgcn_mfma_f32_16x16x32_bf16(afr[0], bfr[ntl][0], acc[mt][ntl], 0,0,0);
        acc[mt][ntl] = __builtin_amdgcn_mfma_f32_16x16x32_bf16(afr[1], bfr[ntl][1], acc[mt][ntl], 0,0,0);
      }
    }
  }
  __syncthreads();

  // ---- P3: frag writeout — xi -> uB[67][129], z -> uA[64][132] ----
  if (wv < 4) {
    #pragma unroll
    for (int mt=0; mt<5; ++mt)
      #pragma unroll
      for (int ntl=0; ntl<2; ++ntl)
        #pragma unroll
        for (int r=0; r<4; ++r){
          int m = mt*16 + (lane>>4)*4 + r;
          if (m <= 66) uB[m*129 + (wv*2+ntl)*16 + (lane&15)] = acc[mt][ntl][r];
        }
  } else {
    #pragma unroll
    for (int mt=0; mt<5; ++mt)
      #pragma unroll
      for (int ntl=0; ntl<2; ++ntl)
        #pragma unroll
        for (int r=0; r<4; ++r){
          int m = mt*16 + (lane>>4)*4 + r;
          if (m >= 3 && m <= 66)
            uA[(m-3)*132 + ((wv-4)*2+ntl)*16 + (lane&15)] = acc[mt][ntl][r];
        }
  }
  __syncthreads();

  // ---- P3b: z -> global, coalesced ----
  #pragma unroll
  for (int it=0; it<4; ++it) {
    int f = it*512 + tid;
    int row = f >> 5, c0 = (f & 31) * 4;
    float4 v = *(const float4*)&uA[row*132 + c0];
    *(float4*)&zg[(rbase + row)*DI + c0] = v;
  }
  __syncthreads();

  // ---- P4: causal conv + silu -> xcg fp32 + bf16 hi/lo in uA ----
  {
    const int d = tid & 127, rh = tid >> 7;
    float4 cw = *(const float4*)(conv_w + (size_t)(i*DI + d)*KC);
    const float cb = conv_b[i*DI + d];
    #pragma unroll 4
    for (int rr=0; rr<16; ++rr) {
      int lr = 3 + rh*16 + rr;
      float v0 = uB[(lr-3)*129 + d];
      float v1 = uB[(lr-2)*129 + d];
      float v2 = uB[(lr-1)*129 + d];
      float v3 = uB[(lr  )*129 + d];
      float a = cb + cw.x*v0 + cw.y*v1 + cw.z*v2 + cw.w*v3;
      float xc = a * fsig(a);
      int r = lr - 3;
      xcg[(rbase + r)*DI + d] = xc;
      __bf16 hh = (__bf16)xc;
      __bf16 ll = (__bf16)(xc - (float)hh);
      int off = (r*256 + d*2) ^ ((r&7)<<4);
      *(__bf16*)((char*)uA + off) = hh;
      *(__bf16*)((char*)uA + off + 16384) = ll;
    }
  }
  __syncthreads();

  // ---- P5: stage xp_w hi/lo bf16 into uB (xi dead) ----
  for (int e = tid; e < 36*32; e += 512) {
    int j = e >> 5, k0 = (e & 31)*4;
    float4 w = *(const float4*)(xp_w + ((size_t)(i*36) + j)*DI + k0);
    float vv[4] = {w.x, w.y, w.z, w.w};
    bf16x4v hv, lv;
    #pragma unroll
    for (int k=0;k<4;++k){
      __bf16 hh = (__bf16)vv[k];
      hv[k] = hh;
      lv[k] = (__bf16)(vv[k] - (float)hh);
    }
    int off = (j*256 + k0*2) ^ ((j&7)<<4);
    *(bf16x4v*)((char*)uB + off) = hv;
    *(bf16x4v*)((char*)uB + off + 12288) = lv;
  }
  __syncthreads();

  // ---- P6: x_proj split-precision MFMA; dtl->uA, B->Bg, C->Cg ----
  for (int t = wv; t < 12; t += 8) {
    int mt = t & 3, nt = t >> 2;
    f32x4 a2 = {0.f,0.f,0.f,0.f};
    #pragma unroll
    for (int kt=0; kt<4; ++kt){
      int row = mt*16 + (lane&15);
      int ab = (row*256 + kt*64 + (lane>>4)*16) ^ ((row&7)<<4);
      bf16x8v ah = *(const bf16x8v*)((const char*)uA + ab);
      bf16x8v al = *(const bf16x8v*)((const char*)uA + ab + 16384);
      int col = nt*16 + (lane&15);
      int bby = (col*256 + kt*64 + (lane>>4)*16) ^ ((col&7)<<4);
      bf16x8v bh = *(const bf16x8v*)((const char*)uB + bby);
      bf16x8v bl = *(const bf16x8v*)((const char*)uB + bby + 12288);
      a2 = __builtin_amdgcn_mfma_f32_16x16x32_bf16(ah, bh, a2, 0,0,0);
      a2 = __builtin_amdgcn_mfma_f32_16x16x32_bf16(al, bh, a2, 0,0,0);
      a2 = __builtin_amdgcn_mfma_f32_16x16x32_bf16(ah, bl, a2, 0,0,0);
    }
    #pragma unroll
    for (int rg4=0; rg4<4; ++rg4){
      int row = mt*16 + (lane>>4)*4 + rg4;
      int j = nt*16 + (lane&15);
      float val = a2[rg4];
      if (j < 4) uA[8448 + row*4 + j] = val;
      else if (j < 20) Bg[(rbase+row)*NS + (j-4)] = val;
      else if (j < 36) Cg[(rbase+row)*NS + (j-20)] = val;
    }
  }
  __syncthreads();

  // ---- P7: dt = softplus(dtl @ dtp_w^T + bias), all 512 threads ----
  #pragma unroll 4
  for (int it=0; it<16; ++it) {
    int e = it*512 + tid;
    int r = e >> 7, d = e & 127;
    float4 dl = *(const float4*)&uA[8448 + r*4];
    float4 w  = *(const float4*)(dtp_w + (size_t)(i*DI + d)*RK);
    float a = dt_b[i*DI + d] + dot4(w, dl);
    dtg[(rbase + r)*DI + d] = (a > 20.f) ? a : log1pf(__expf(a));
  }
}

// ---------------------------------------------------------------------------
// KB v2: pass1 local scan, NO LDS / NO barriers — direct global reads
// (data is L2/L3-resident; 4-row prefetch groups; B broadcast via cache)
// ---------------------------------------------------------------------------
__global__ __launch_bounds__(256) void kb_pass1(
    const float* __restrict__ dtg, const float* __restrict__ xcg, const float* __restrict__ Bg,
    const float* __restrict__ A_log,
    float* __restrict__ Pm, float* __restrict__ hend)
{
  const int tid = threadIdx.x;
  const int bx = blockIdx.x;
  const int c = bx % NC; const int i = (bx/NC)&1; const int b = bx/(2*NC);
  const int d = tid >> 1, half = tid & 1, n0 = half*8;
  float a[8], h[8];
  bool afast = true;
  #pragma unroll
  for (int n=0;n<8;++n){
    a[n] = -__expf(A_log[((size_t)(i*DI)+d)*NS + n0+n]);
    float tgt = (float)(n0+n+1);
    afast = afast && (fabsf(a[n] + tgt) <= 1e-4f*tgt);
    h[n] = 0.f;
  }
  float S = 0.f;
  const size_t rb = ((size_t)(b*2+i)*Lx + (size_t)c*CT);
  for (int r4 = 0; r4 < CT; r4 += 4){
    float dt4[4], x4[4];
    #pragma unroll
    for (int k=0;k<4;++k){
      size_t g = (rb + r4 + k)*DI + d;
      dt4[k] = dtg[g];
      x4[k]  = xcg[g];
    }
    #pragma unroll
    for (int k=0;k<4;++k){
      float dtt = dt4[k];
      float u = dtt * x4[k];
      S += dtt;
      const float* bp = &Bg[(rb + r4 + k)*NS + n0];
      float4 b0 = *(const float4*)bp;
      float4 b1 = *(const float4*)(bp+4);
      float bb[8] = {b0.x,b0.y,b0.z,b0.w,b1.x,b1.y,b1.z,b1.w};
      if (afast){
        float rr = __expf(-dtt);
        float dA;
        if (half){ float r2=rr*rr, r4v=r2*r2; dA = r4v*r4v*rr; } else dA = rr;
        h[0] = fmaf(dA, h[0], u*bb[0]);
        #pragma unroll
        for (int n=1;n<8;++n){ dA *= rr; h[n] = fmaf(dA, h[n], u*bb[n]); }
      } else {
        #pragma unroll
        for (int n=0;n<8;++n){
          float dA = __expf(a[n]*dtt);
          h[n] = fmaf(dA, h[n], u*bb[n]);
        }
      }
    }
  }
  size_t ob = (((size_t)(b*2+i)*NC + c)*DI + d)*NS + n0;
  #pragma unroll
  for (int n=0;n<8;++n){
    Pm[ob+n] = __expf(a[n]*S);
    hend[ob+n] = h[n];
  }
}

// ---------------------------------------------------------------------------
// KC: pass2 — propagate chunk boundary states; h0 written IN PLACE over Pm
// ---------------------------------------------------------------------------
__global__ __launch_bounds__(256) void kc_pass2(
    float* __restrict__ Pm, const float* __restrict__ hend)
{
  const int tid = threadIdx.x;
  const int bi = blockIdx.x;
  const int d = tid>>1, n0 = (tid&1)*8;
  float h[8];
  #pragma unroll
  for (int n=0;n<8;++n) h[n]=0.f;
  for (int c=0;c<NC;++c){
    size_t ob = (((size_t)bi*NC + c)*DI + d)*NS + n0;
    float p[8], hev[8];
    #pragma unroll
    for (int n=0;n<8;++n){ p[n]=Pm[ob+n]; hev[n]=hend[ob+n]; }
    #pragma unroll
    for (int n=0;n<8;++n){ Pm[ob+n] = h[n]; h[n] = fmaf(p[n], h[n], hev[n]); }
  }
}

// ---------------------------------------------------------------------------
// KD v2: pass3 scan, NO LDS / NO barriers — direct global reads; y -> dtg.
// In-place safety: column (r,d) of dtg is read only by lanes 2d/2d+1 of one
// wave, and the group's loads precede its stores in program order (lockstep).
// ---------------------------------------------------------------------------
__global__ __launch_bounds__(256) void kd_pass3(
    const float* dtg, const float* __restrict__ xcg, const float* __restrict__ Bg,
    const float* __restrict__ Cg, const float* __restrict__ A_log, const float* __restrict__ Dp,
    const float* __restrict__ h0, const float* __restrict__ zg, float* yout)
{
  const int tid = threadIdx.x;
  const int bx = blockIdx.x;
  const int c = bx % NC; const int i = (bx/NC)&1; const int b = bx/(2*NC);
  const int d = tid >> 1, half = tid & 1, n0 = half*8;
  float a[8], h[8];
  bool afast = true;
  size_t hb = (((size_t)(b*2+i)*NC + c)*DI + d)*NS + n0;
  #pragma unroll
  for (int n=0;n<8;++n){
    a[n] = -__expf(A_log[((size_t)(i*DI)+d)*NS + n0+n]);
    float tgt = (float)(n0+n+1);
    afast = afast && (fabsf(a[n] + tgt) <= 1e-4f*tgt);
    h[n] = h0[hb+n];
  }
  const float Dd = Dp[i*DI + d];
  const size_t rb = ((size_t)(b*2+i)*Lx + (size_t)c*CT);
  for (int r4 = 0; r4 < CT; r4 += 4){
    float dt4[4], x4[4], z4[4];
    #pragma unroll
    for (int k=0;k<4;++k){
      size_t g = (rb + r4 + k)*DI + d;
      dt4[k] = dtg[g];
      x4[k]  = xcg[g];
      z4[k]  = zg[g];
    }
    #pragma unroll
    for (int k=0;k<4;++k){
      float dtt = dt4[k];
      float xcv = x4[k];
      float u = dtt * xcv;
      const float* bp = &Bg[(rb + r4 + k)*NS + n0];
      const float* cp = &Cg[(rb + r4 + k)*NS + n0];
      float4 b0 = *(const float4*)bp;
      float4 b1 = *(const float4*)(bp+4);
      float4 c0 = *(const float4*)cp;
      float4 c1 = *(const float4*)(cp+4);
      float bb[8] = {b0.x,b0.y,b0.z,b0.w,b1.x,b1.y,b1.z,b1.w};
      float cc[8] = {c0.x,c0.y,c0.z,c0.w,c1.x,c1.y,c1.z,c1.w};
      float part = 0.f;
      if (afast){
        float rr = __expf(-dtt);
        float dA;
        if (half){ float r2=rr*rr, r4v=r2*r2; dA = r4v*r4v*rr; } else dA = rr;
        h[0] = fmaf(dA, h[0], u*bb[0]);
        part = fmaf(h[0], cc[0], part);
        #pragma unroll
        for (int n=1;n<8;++n){
          dA *= rr;
          h[n] = fmaf(dA, h[n], u*bb[n]);
          part = fmaf(h[n], cc[n], part);
        }
      } else {
        #pragma unroll
        for (int n=0;n<8;++n){
          float dA = __expf(a[n]*dtt);
          h[n] = fmaf(dA, h[n], u*bb[n]);
          part = fmaf(h[n], cc[n], part);
        }
      }
      float y = part + __shfl_xor(part, 1);
      if (half == 0){
        float zz = z4[k];
        yout[(rb + r4 + k)*DI + d] = fmaf(xcv, Dd, y) * (zz * fsig(zz));
      }
    }
  }
}

// ---------------------------------------------------------------------------
// KE: out-proj, sum both directions (dir1 read flipped)
// ---------------------------------------------------------------------------
__global__ __launch_bounds__(256) void ke_out(
    const float* __restrict__ yg, const float* __restrict__ ow, float* __restrict__ out)
{
  __shared__ float s_y0[TRE][DI];
  __shared__ float s_y1[TRE][DI];
  const int tid = threadIdx.x;
  const int bx = blockIdx.x;
  const int ntile = Lx / TRE;
  const int tile = bx % ntile; const int b = bx / ntile;
  const int l0 = tile * TRE;
  #pragma unroll
  for (int it=0, e=tid; it<(TRE*DI)/256; ++it, e+=256){
    int r = e >> 7, dd = e & (DI-1);
    s_y0[r][dd] = yg[((size_t)(b*2+0)*Lx + (size_t)(l0+r))*DI + dd];
    s_y1[r][dd] = yg[((size_t)(b*2+1)*Lx + (size_t)(Lx-1-(l0+r)))*DI + dd];
  }
  __syncthreads();
  const int m = tid & 63, r0 = tid >> 6;
  const float4* w0 = (const float4*)(ow + (size_t)m*DI);
  const float4* w1 = (const float4*)(ow + (size_t)(DM+m)*DI);
  float acc[4] = {0.f,0.f,0.f,0.f};
  #pragma unroll
  for (int k=0;k<DI/4;++k){
    float4 a0 = w0[k], a1 = w1[k];
    #pragma unroll
    for (int j=0;j<4;++j){
      const float4 y0 = *(const float4*)(&s_y0[r0+j*4][k*4]);
      const float4 y1 = *(const float4*)(&s_y1[r0+j*4][k*4]);
      acc[j] += dot4(a0,y0) + dot4(a1,y1);
    }
  }
  #pragma unroll
  for (int j=0;j<4;++j)
    out[((size_t)b*Lx + (size_t)(l0 + r0 + j*4))*DM + m] = acc[j];
}

extern "C" void kernel_launch(void* const* d_in, const int* in_sizes, int n_in,
                              void* d_out, int out_size, void* d_ws, size_t ws_size,
                              hipStream_t stream)
{
  const float* x      = (const float*)d_in[0];
  const float* ln_g   = (const float*)d_in[1];
  const float* ln_b   = (const float*)d_in[2];
  const float* in_w   = (const float*)d_in[3];
  const float* conv_w = (const float*)d_in[4];
  const float* conv_b = (const float*)d_in[5];
  const float* xp_w   = (const float*)d_in[6];
  const float* dtp_w  = (const float*)d_in[7];
  const float* dt_b   = (const float*)d_in[8];
  const float* A_log  = (const float*)d_in[9];
  const float* Dp     = (const float*)d_in[10];
  const float* ow     = (const float*)d_in[11];
  float* out = (float*)d_out;
  float* ws = (float*)d_ws;
  const size_t NBD = (size_t)Bsz*2*Lx*DI;     // 8,388,608
  const size_t NBN = (size_t)Bsz*2*Lx*NS;     // 1,048,576
  float* xcg = ws;
  float* dtg = xcg + NBD;
  float* zg  = dtg + NBD;
  float* Bg  = zg + NBD;
  float* Cg  = Bg + NBN;
  float* Pm  = Cg + NBN;          // Bsz*2*NC*DI*NS = 2,097,152 floats; becomes h0 after kc
  float* he  = out;               // hend staged in d_out (fully overwritten by ke)

  a1_front<<<dim3(Bsz*2*(Lx/64)), dim3(512), 0, stream>>>(
      x, ln_g, ln_b, in_w, conv_w, conv_b, xp_w, dtp_w, dt_b, xcg, dtg, zg, Bg, Cg);
  kb_pass1<<<dim3(Bsz*2*NC), dim3(256), 0, stream>>>(dtg, xcg, Bg, A_log, Pm, he);
  kc_pass2<<<dim3(Bsz*2), dim3(256), 0, stream>>>(Pm, he);
  kd_pass3<<<dim3(Bsz*2*NC), dim3(256), 0, stream>>>(dtg, xcg, Bg, Cg, A_log, Dp, Pm, zg, dtg);
  ke_out<<<dim3(Bsz*(Lx/TRE)), dim3(256), 0, stream>>>(dtg, ow, out);
}

// Round 10
// 165.271 us; speedup vs baseline: 1.4577x; 1.3465x over previous
//
#include <hip/hip_runtime.h>

#define Bsz 8
#define Lx 4096
#define DM 64
#define DI 128
#define NS 16
#define RK 4
#define KC 4
#define NC 64
#define CT 64

typedef __attribute__((ext_vector_type(8))) __bf16 bf16x8v;
typedef __attribute__((ext_vector_type(4))) __bf16 bf16x4v;
typedef __attribute__((ext_vector_type(4))) float f32x4;

__device__ __forceinline__ float fsig(float x){ return 1.f/(1.f+__expf(-x)); }
__device__ __forceinline__ float dot4(float4 a, float4 b){
  return fmaf(a.x,b.x, fmaf(a.y,b.y, fmaf(a.z,b.z, a.w*b.w)));
}

// ---------------------------------------------------------------------------
// A1 v8: LN + in_proj MFMA + conv + x_proj split-bf16 MFMA + dt (all-thread).
// ---------------------------------------------------------------------------
__global__ __launch_bounds__(512) void a1_front(
    const float* __restrict__ x, const float* __restrict__ ln_g, const float* __restrict__ ln_b,
    const float* __restrict__ in_w, const float* __restrict__ conv_w, const float* __restrict__ conv_b,
    const float* __restrict__ xp_w, const float* __restrict__ dtp_w, const float* __restrict__ dt_b,
    float* __restrict__ xcg, float* __restrict__ dtg, float* __restrict__ zg,
    float* __restrict__ Bg, float* __restrict__ Cg)
{
  __shared__ float uA[8704];
  __shared__ float uB[8704];
  const int tid = threadIdx.x;
  const int bx = blockIdx.x;
  const int tile = bx & 63;
  const int i = (bx >> 6) & 1;
  const int b = bx >> 7;
  const int l0 = tile * 64;
  const size_t rbase = (size_t)(b*2+i)*Lx + l0;

  // ---- P1: LN -> bf16 X (uA swz) ; W -> bf16 (uB swz, packed 8B stores) ----
  {
    const int wv8 = tid >> 6, lane = tid & 63;
    const float gg = ln_g[lane], bb = ln_b[lane];
    for (int lr = wv8; lr < 80; lr += 8) {
      float v = 0.f;
      int l = l0 - 3 + lr;
      if (lr < 67 && l >= 0) {
        int pl = i ? (Lx-1-l) : l;
        v = x[((size_t)b*Lx + pl)*DM + lane];
        float s = v, s2 = v*v;
        #pragma unroll
        for (int off=32; off; off>>=1){ s += __shfl_xor(s,off); s2 += __shfl_xor(s2,off); }
        float mu = s * (1.f/DM);
        float rs = rsqrtf(s2*(1.f/DM) - mu*mu + 1e-5f);
        v = (v-mu)*rs*gg + bb;
      }
      *(__bf16*)((char*)uA + ((lr*128 + lane*2) ^ ((lr&7)<<4))) = (__bf16)v;
    }
    #pragma unroll
    for (int it=0; it<8; ++it) {
      int g = it*512 + tid;
      int c = g >> 4, q = g & 15;
      float4 w = *(const float4*)(in_w + ((size_t)(i*2*DI) + c)*DM + q*4);
      bf16x4v hv;
      hv[0]=(__bf16)w.x; hv[1]=(__bf16)w.y; hv[2]=(__bf16)w.z; hv[3]=(__bf16)w.w;
      *(bf16x4v*)((char*)uB + ((c*128 + q*8) ^ ((c&7)<<4))) = hv;
    }
  }
  __syncthreads();

  // ---- P2: in_proj via MFMA ----
  const int lane = tid & 63, wv = tid >> 6;
  f32x4 acc[5][2];
  {
    f32x4 z4 = {0.f, 0.f, 0.f, 0.f};
    #pragma unroll
    for (int mt=0; mt<5; ++mt){ acc[mt][0] = z4; acc[mt][1] = z4; }
    bf16x8v bfr[2][2];
    #pragma unroll
    for (int ntl=0; ntl<2; ++ntl)
      #pragma unroll
      for (int kt=0; kt<2; ++kt){
        int c = (wv*2+ntl)*16 + (lane&15);
        int byt = (c*128 + kt*64 + (lane>>4)*16) ^ ((c&7)<<4);
        bfr[ntl][kt] = *(const bf16x8v*)((const char*)uB + byt);
      }
    #pragma unroll
    for (int mt=0; mt<5; ++mt){
      bf16x8v afr[2];
      #pragma unroll
      for (int kt=0; kt<2; ++kt){
        int row = mt*16 + (lane&15);
        int byt = (row*128 + kt*64 + (lane>>4)*16) ^ ((row&7)<<4);
        afr[kt] = *(const bf16x8v*)((const char*)uA + byt);
      }
      #pragma unroll
      for (int ntl=0; ntl<2; ++ntl){
        acc[mt][ntl] = __builtin_amdgcn_mfma_f32_16x16x32_bf16(afr[0], bfr[ntl][0], acc[mt][ntl], 0,0,0);
        acc[mt][ntl] = __builtin_amdgcn_mfma_f32_16x16x32_bf16(afr[1], bfr[ntl][1], acc[mt][ntl], 0,0,0);
      }
    }
  }
  __syncthreads();

  // ---- P3: frag writeout — xi -> uB[67][129], z -> uA[64][132] ----
  if (wv < 4) {
    #pragma unroll
    for (int mt=0; mt<5; ++mt)
      #pragma unroll
      for (int ntl=0; ntl<2; ++ntl)
        #pragma unroll
        for (int r=0; r<4; ++r){
          int m = mt*16 + (lane>>4)*4 + r;
          if (m <= 66) uB[m*129 + (wv*2+ntl)*16 + (lane&15)] = acc[mt][ntl][r];
        }
  } else {
    #pragma unroll
    for (int mt=0; mt<5; ++mt)
      #pragma unroll
      for (int ntl=0; ntl<2; ++ntl)
        #pragma unroll
        for (int r=0; r<4; ++r){
          int m = mt*16 + (lane>>4)*4 + r;
          if (m >= 3 && m <= 66)
            uA[(m-3)*132 + ((wv-4)*2+ntl)*16 + (lane&15)] = acc[mt][ntl][r];
        }
  }
  __syncthreads();

  // ---- P3b: z -> global, coalesced ----
  #pragma unroll
  for (int it=0; it<4; ++it) {
    int f = it*512 + tid;
    int row = f >> 5, c0 = (f & 31) * 4;
    float4 v = *(const float4*)&uA[row*132 + c0];
    *(float4*)&zg[(rbase + row)*DI + c0] = v;
  }
  __syncthreads();

  // ---- P4: causal conv + silu -> xcg fp32 + bf16 hi/lo in uA ----
  {
    const int d = tid & 127, rh = tid >> 7;
    float4 cw = *(const float4*)(conv_w + (size_t)(i*DI + d)*KC);
    const float cb = conv_b[i*DI + d];
    #pragma unroll 4
    for (int rr=0; rr<16; ++rr) {
      int lr = 3 + rh*16 + rr;
      float v0 = uB[(lr-3)*129 + d];
      float v1 = uB[(lr-2)*129 + d];
      float v2 = uB[(lr-1)*129 + d];
      float v3 = uB[(lr  )*129 + d];
      float a = cb + cw.x*v0 + cw.y*v1 + cw.z*v2 + cw.w*v3;
      float xc = a * fsig(a);
      int r = lr - 3;
      xcg[(rbase + r)*DI + d] = xc;
      __bf16 hh = (__bf16)xc;
      __bf16 ll = (__bf16)(xc - (float)hh);
      int off = (r*256 + d*2) ^ ((r&7)<<4);
      *(__bf16*)((char*)uA + off) = hh;
      *(__bf16*)((char*)uA + off + 16384) = ll;
    }
  }
  __syncthreads();

  // ---- P5: stage xp_w hi/lo bf16 into uB (xi dead) ----
  for (int e = tid; e < 36*32; e += 512) {
    int j = e >> 5, k0 = (e & 31)*4;
    float4 w = *(const float4*)(xp_w + ((size_t)(i*36) + j)*DI + k0);
    float vv[4] = {w.x, w.y, w.z, w.w};
    bf16x4v hv, lv;
    #pragma unroll
    for (int k=0;k<4;++k){
      __bf16 hh = (__bf16)vv[k];
      hv[k] = hh;
      lv[k] = (__bf16)(vv[k] - (float)hh);
    }
    int off = (j*256 + k0*2) ^ ((j&7)<<4);
    *(bf16x4v*)((char*)uB + off) = hv;
    *(bf16x4v*)((char*)uB + off + 12288) = lv;
  }
  __syncthreads();

  // ---- P6: x_proj split-precision MFMA; dtl->uA, B->Bg, C->Cg ----
  for (int t = wv; t < 12; t += 8) {
    int mt = t & 3, nt = t >> 2;
    f32x4 a2 = {0.f,0.f,0.f,0.f};
    #pragma unroll
    for (int kt=0; kt<4; ++kt){
      int row = mt*16 + (lane&15);
      int ab = (row*256 + kt*64 + (lane>>4)*16) ^ ((row&7)<<4);
      bf16x8v ah = *(const bf16x8v*)((const char*)uA + ab);
      bf16x8v al = *(const bf16x8v*)((const char*)uA + ab + 16384);
      int col = nt*16 + (lane&15);
      int bby = (col*256 + kt*64 + (lane>>4)*16) ^ ((col&7)<<4);
      bf16x8v bh = *(const bf16x8v*)((const char*)uB + bby);
      bf16x8v bl = *(const bf16x8v*)((const char*)uB + bby + 12288);
      a2 = __builtin_amdgcn_mfma_f32_16x16x32_bf16(ah, bh, a2, 0,0,0);
      a2 = __builtin_amdgcn_mfma_f32_16x16x32_bf16(al, bh, a2, 0,0,0);
      a2 = __builtin_amdgcn_mfma_f32_16x16x32_bf16(ah, bl, a2, 0,0,0);
    }
    #pragma unroll
    for (int rg4=0; rg4<4; ++rg4){
      int row = mt*16 + (lane>>4)*4 + rg4;
      int j = nt*16 + (lane&15);
      float val = a2[rg4];
      if (j < 4) uA[8448 + row*4 + j] = val;
      else if (j < 20) Bg[(rbase+row)*NS + (j-4)] = val;
      else if (j < 36) Cg[(rbase+row)*NS + (j-20)] = val;
    }
  }
  __syncthreads();

  // ---- P7: dt = softplus(dtl @ dtp_w^T + bias), all 512 threads ----
  #pragma unroll 4
  for (int it=0; it<16; ++it) {
    int e = it*512 + tid;
    int r = e >> 7, d = e & 127;
    float4 dl = *(const float4*)&uA[8448 + r*4];
    float4 w  = *(const float4*)(dtp_w + (size_t)(i*DI + d)*RK);
    float a = dt_b[i*DI + d] + dot4(w, dl);
    dtg[(rbase + r)*DI + d] = (a > 20.f) ? a : log1pf(__expf(a));
  }
}

// ---------------------------------------------------------------------------
// KB v2: pass1 local scan, NO LDS / NO barriers — direct global reads
// ---------------------------------------------------------------------------
__global__ __launch_bounds__(256) void kb_pass1(
    const float* __restrict__ dtg, const float* __restrict__ xcg, const float* __restrict__ Bg,
    const float* __restrict__ A_log,
    float* __restrict__ Pm, float* __restrict__ hend)
{
  const int tid = threadIdx.x;
  const int bx = blockIdx.x;
  const int c = bx % NC; const int i = (bx/NC)&1; const int b = bx/(2*NC);
  const int d = tid >> 1, half = tid & 1, n0 = half*8;
  float a[8], h[8];
  bool afast = true;
  #pragma unroll
  for (int n=0;n<8;++n){
    a[n] = -__expf(A_log[((size_t)(i*DI)+d)*NS + n0+n]);
    float tgt = (float)(n0+n+1);
    afast = afast && (fabsf(a[n] + tgt) <= 1e-4f*tgt);
    h[n] = 0.f;
  }
  float S = 0.f;
  const size_t rb = ((size_t)(b*2+i)*Lx + (size_t)c*CT);
  for (int r4 = 0; r4 < CT; r4 += 4){
    float dt4[4], x4[4];
    #pragma unroll
    for (int k=0;k<4;++k){
      size_t g = (rb + r4 + k)*DI + d;
      dt4[k] = dtg[g];
      x4[k]  = xcg[g];
    }
    #pragma unroll
    for (int k=0;k<4;++k){
      float dtt = dt4[k];
      float u = dtt * x4[k];
      S += dtt;
      const float* bp = &Bg[(rb + r4 + k)*NS + n0];
      float4 b0 = *(const float4*)bp;
      float4 b1 = *(const float4*)(bp+4);
      float bb[8] = {b0.x,b0.y,b0.z,b0.w,b1.x,b1.y,b1.z,b1.w};
      if (afast){
        float rr = __expf(-dtt);
        float dA;
        if (half){ float r2=rr*rr, r4v=r2*r2; dA = r4v*r4v*rr; } else dA = rr;
        h[0] = fmaf(dA, h[0], u*bb[0]);
        #pragma unroll
        for (int n=1;n<8;++n){ dA *= rr; h[n] = fmaf(dA, h[n], u*bb[n]); }
      } else {
        #pragma unroll
        for (int n=0;n<8;++n){
          float dA = __expf(a[n]*dtt);
          h[n] = fmaf(dA, h[n], u*bb[n]);
        }
      }
    }
  }
  size_t ob = (((size_t)(b*2+i)*NC + c)*DI + d)*NS + n0;
  #pragma unroll
  for (int n=0;n<8;++n){
    Pm[ob+n] = __expf(a[n]*S);
    hend[ob+n] = h[n];
  }
}

// ---------------------------------------------------------------------------
// KC: pass2 — propagate chunk boundary states; h0 written IN PLACE over Pm
// ---------------------------------------------------------------------------
__global__ __launch_bounds__(256) void kc_pass2(
    float* __restrict__ Pm, const float* __restrict__ hend)
{
  const int tid = threadIdx.x;
  const int bi = blockIdx.x;
  const int d = tid>>1, n0 = (tid&1)*8;
  float h[8];
  #pragma unroll
  for (int n=0;n<8;++n) h[n]=0.f;
  for (int c=0;c<NC;++c){
    size_t ob = (((size_t)bi*NC + c)*DI + d)*NS + n0;
    float p[8], hev[8];
    #pragma unroll
    for (int n=0;n<8;++n){ p[n]=Pm[ob+n]; hev[n]=hend[ob+n]; }
    #pragma unroll
    for (int n=0;n<8;++n){ Pm[ob+n] = h[n]; h[n] = fmaf(p[n], h[n], hev[n]); }
  }
}

// ---------------------------------------------------------------------------
// KD v2: pass3 scan, NO LDS / NO barriers — direct global reads; y -> dtg.
// ---------------------------------------------------------------------------
__global__ __launch_bounds__(256) void kd_pass3(
    const float* dtg, const float* __restrict__ xcg, const float* __restrict__ Bg,
    const float* __restrict__ Cg, const float* __restrict__ A_log, const float* __restrict__ Dp,
    const float* __restrict__ h0, const float* __restrict__ zg, float* yout)
{
  const int tid = threadIdx.x;
  const int bx = blockIdx.x;
  const int c = bx % NC; const int i = (bx/NC)&1; const int b = bx/(2*NC);
  const int d = tid >> 1, half = tid & 1, n0 = half*8;
  float a[8], h[8];
  bool afast = true;
  size_t hb = (((size_t)(b*2+i)*NC + c)*DI + d)*NS + n0;
  #pragma unroll
  for (int n=0;n<8;++n){
    a[n] = -__expf(A_log[((size_t)(i*DI)+d)*NS + n0+n]);
    float tgt = (float)(n0+n+1);
    afast = afast && (fabsf(a[n] + tgt) <= 1e-4f*tgt);
    h[n] = h0[hb+n];
  }
  const float Dd = Dp[i*DI + d];
  const size_t rb = ((size_t)(b*2+i)*Lx + (size_t)c*CT);
  for (int r4 = 0; r4 < CT; r4 += 4){
    float dt4[4], x4[4], z4[4];
    #pragma unroll
    for (int k=0;k<4;++k){
      size_t g = (rb + r4 + k)*DI + d;
      dt4[k] = dtg[g];
      x4[k]  = xcg[g];
      z4[k]  = zg[g];
    }
    #pragma unroll
    for (int k=0;k<4;++k){
      float dtt = dt4[k];
      float xcv = x4[k];
      float u = dtt * xcv;
      const float* bp = &Bg[(rb + r4 + k)*NS + n0];
      const float* cp = &Cg[(rb + r4 + k)*NS + n0];
      float4 b0 = *(const float4*)bp;
      float4 b1 = *(const float4*)(bp+4);
      float4 c0 = *(const float4*)cp;
      float4 c1 = *(const float4*)(cp+4);
      float bb[8] = {b0.x,b0.y,b0.z,b0.w,b1.x,b1.y,b1.z,b1.w};
      float cc[8] = {c0.x,c0.y,c0.z,c0.w,c1.x,c1.y,c1.z,c1.w};
      float part = 0.f;
      if (afast){
        float rr = __expf(-dtt);
        float dA;
        if (half){ float r2=rr*rr, r4v=r2*r2; dA = r4v*r4v*rr; } else dA = rr;
        h[0] = fmaf(dA, h[0], u*bb[0]);
        part = fmaf(h[0], cc[0], part);
        #pragma unroll
        for (int n=1;n<8;++n){
          dA *= rr;
          h[n] = fmaf(dA, h[n], u*bb[n]);
          part = fmaf(h[n], cc[n], part);
        }
      } else {
        #pragma unroll
        for (int n=0;n<8;++n){
          float dA = __expf(a[n]*dtt);
          h[n] = fmaf(dA, h[n], u*bb[n]);
          part = fmaf(h[n], cc[n], part);
        }
      }
      float y = part + __shfl_xor(part, 1);
      if (half == 0){
        float zz = z4[k];
        yout[(rb + r4 + k)*DI + d] = fmaf(xcv, Dd, y) * (zz * fsig(zz));
      }
    }
  }
}

// ---------------------------------------------------------------------------
// KE v2: out-proj via bf16 MFMA. Block = 32 rows; K=256 (dir0 | dir1-flipped).
// Y and W staged COALESCED into LDS bf16 (swz); fixes the 512B-stride weight
// gather that made v1 TA-bound (72 us, VALU 25%, HBM 3%).
// ---------------------------------------------------------------------------
__global__ __launch_bounds__(256) void ke_out(
    const float* __restrict__ yg, const float* __restrict__ ow, float* __restrict__ out)
{
  __shared__ char sY[16384];   // [32 rows][256 k] bf16, swz
  __shared__ char sW[32768];   // [64 ch ][256 k] bf16, swz
  const int tid = threadIdx.x;
  const int bx = blockIdx.x;
  const int tile = bx & 127; const int b = bx >> 7;
  const int l0 = tile * 32;
  // stage W (4096 float4 tasks, coalesced)
  #pragma unroll
  for (int it=0; it<16; ++it){
    int e = it*256 + tid;
    int dir = e >> 11, c = (e >> 5) & 63, q = e & 31;
    float4 w = *(const float4*)(ow + ((size_t)(dir*DM + c))*DI + q*4);
    bf16x4v hv; hv[0]=(__bf16)w.x; hv[1]=(__bf16)w.y; hv[2]=(__bf16)w.z; hv[3]=(__bf16)w.w;
    *(bf16x4v*)(sW + ((c*512 + dir*256 + q*8) ^ ((c&7)<<4))) = hv;
  }
  // stage Y (2048 float4 tasks; dir1 rows flipped)
  #pragma unroll
  for (int it=0; it<8; ++it){
    int e = it*256 + tid;
    int dir = e >> 10, r = (e >> 5) & 31, q = e & 31;
    size_t row = dir ? ((size_t)(b*2+1)*Lx + (size_t)(Lx-1-(l0+r)))
                     : ((size_t)(b*2  )*Lx + (size_t)(l0+r));
    float4 v = *(const float4*)(yg + row*DI + q*4);
    bf16x4v hv; hv[0]=(__bf16)v.x; hv[1]=(__bf16)v.y; hv[2]=(__bf16)v.z; hv[3]=(__bf16)v.w;
    *(bf16x4v*)(sY + ((r*512 + dir*256 + q*8) ^ ((r&7)<<4))) = hv;
  }
  __syncthreads();
  const int lane = tid & 63, wv = tid >> 6;
  #pragma unroll
  for (int t=0; t<2; ++t){
    int T = wv*2 + t, mt = T >> 2, nt = T & 3;
    f32x4 acc = {0.f,0.f,0.f,0.f};
    #pragma unroll
    for (int kt=0; kt<8; ++kt){
      int row = mt*16 + (lane&15);
      bf16x8v av = *(const bf16x8v*)(sY + ((row*512 + kt*64 + (lane>>4)*16) ^ ((row&7)<<4)));
      int ch = nt*16 + (lane&15);
      bf16x8v wvv = *(const bf16x8v*)(sW + ((ch*512 + kt*64 + (lane>>4)*16) ^ ((ch&7)<<4)));
      acc = __builtin_amdgcn_mfma_f32_16x16x32_bf16(av, wvv, acc, 0,0,0);
    }
    #pragma unroll
    for (int r=0; r<4; ++r){
      int m = mt*16 + (lane>>4)*4 + r;
      int ch = nt*16 + (lane&15);
      out[((size_t)b*Lx + (size_t)(l0+m))*DM + ch] = acc[r];
    }
  }
}

extern "C" void kernel_launch(void* const* d_in, const int* in_sizes, int n_in,
                              void* d_out, int out_size, void* d_ws, size_t ws_size,
                              hipStream_t stream)
{
  const float* x      = (const float*)d_in[0];
  const float* ln_g   = (const float*)d_in[1];
  const float* ln_b   = (const float*)d_in[2];
  const float* in_w   = (const float*)d_in[3];
  const float* conv_w = (const float*)d_in[4];
  const float* conv_b = (const float*)d_in[5];
  const float* xp_w   = (const float*)d_in[6];
  const float* dtp_w  = (const float*)d_in[7];
  const float* dt_b   = (const float*)d_in[8];
  const float* A_log  = (const float*)d_in[9];
  const float* Dp     = (const float*)d_in[10];
  const float* ow     = (const float*)d_in[11];
  float* out = (float*)d_out;
  float* ws = (float*)d_ws;
  const size_t NBD = (size_t)Bsz*2*Lx*DI;     // 8,388,608
  const size_t NBN = (size_t)Bsz*2*Lx*NS;     // 1,048,576
  float* xcg = ws;
  float* dtg = xcg + NBD;
  float* zg  = dtg + NBD;
  float* Bg  = zg + NBD;
  float* Cg  = Bg + NBN;
  float* Pm  = Cg + NBN;          // becomes h0 in-place after kc
  float* he  = out;               // hend staged in d_out (fully overwritten by ke)

  a1_front<<<dim3(Bsz*2*(Lx/64)), dim3(512), 0, stream>>>(
      x, ln_g, ln_b, in_w, conv_w, conv_b, xp_w, dtp_w, dt_b, xcg, dtg, zg, Bg, Cg);
  kb_pass1<<<dim3(Bsz*2*NC), dim3(256), 0, stream>>>(dtg, xcg, Bg, A_log, Pm, he);
  kc_pass2<<<dim3(Bsz*2), dim3(256), 0, stream>>>(Pm, he);
  kd_pass3<<<dim3(Bsz*2*NC), dim3(256), 0, stream>>>(dtg, xcg, Bg, Cg, A_log, Dp, Pm, zg, dtg);
  ke_out<<<dim3(Bsz*(Lx/32)), dim3(256), 0, stream>>>(dtg, ow, out);
}

// Round 11
// 147.409 us; speedup vs baseline: 1.6343x; 1.1212x over previous
//
#include <hip/hip_runtime.h>

#define Bsz 8
#define Lx 4096
#define DM 64
#define DI 128
#define NS 16
#define RK 4
#define KC 4
#define NC 64
#define CT 64

typedef __attribute__((ext_vector_type(8))) __bf16 bf16x8v;
typedef __attribute__((ext_vector_type(4))) __bf16 bf16x4v;
typedef __attribute__((ext_vector_type(4))) float f32x4;

__device__ __forceinline__ float fsig(float x){ return 1.f/(1.f+__expf(-x)); }
__device__ __forceinline__ float dot4(float4 a, float4 b){
  return fmaf(a.x,b.x, fmaf(a.y,b.y, fmaf(a.z,b.z, a.w*b.w)));
}

// ---------------------------------------------------------------------------
// A1 v9: LDS 52224 B -> 3 blocks/CU (was 69632 -> 2).
// uA[4864 f]: X bf16 [<=80][128B] swz (P1-P2) | xi-half [35][129] f32 (P3/P4)
//             | xpw hi/lo bf16 @0/+9216B (P5-P6) + dtl f32 @f4608 (18432B..)
// uB[8192 f]: W bf16 [256][128B] swz (P1-P2) | xc hi/lo bf16 @0/+16384B (P4+)
// z written DIRECT from fragments (64B chunks). softplus via __logf.
// ---------------------------------------------------------------------------
__global__ __launch_bounds__(512) void a1_front(
    const float* __restrict__ x, const float* __restrict__ ln_g, const float* __restrict__ ln_b,
    const float* __restrict__ in_w, const float* __restrict__ conv_w, const float* __restrict__ conv_b,
    const float* __restrict__ xp_w, const float* __restrict__ dtp_w, const float* __restrict__ dt_b,
    float* __restrict__ xcg, float* __restrict__ dtg, float* __restrict__ zg,
    float* __restrict__ Bg, float* __restrict__ Cg)
{
  __shared__ float uA[4864];   // 19456 B
  __shared__ float uB[8192];   // 32768 B
  const int tid = threadIdx.x;
  const int bx = blockIdx.x;
  const int tile = bx & 63;
  const int i = (bx >> 6) & 1;
  const int b = bx >> 7;
  const int l0 = tile * 64;
  const size_t rbase = (size_t)(b*2+i)*Lx + l0;

  // ---- P1: LN -> bf16 X (uA swz, rows 0..66) ; W -> bf16 (uB swz) ----
  {
    const int wv8 = tid >> 6, lane = tid & 63;
    const float gg = ln_g[lane], bb = ln_b[lane];
    for (int lr = wv8; lr < 67; lr += 8) {
      float v = 0.f;
      int l = l0 - 3 + lr;
      if (l >= 0) {
        int pl = i ? (Lx-1-l) : l;
        v = x[((size_t)b*Lx + pl)*DM + lane];
        float s = v, s2 = v*v;
        #pragma unroll
        for (int off=32; off; off>>=1){ s += __shfl_xor(s,off); s2 += __shfl_xor(s2,off); }
        float mu = s * (1.f/DM);
        float rs = rsqrtf(s2*(1.f/DM) - mu*mu + 1e-5f);
        v = (v-mu)*rs*gg + bb;
      }
      *(__bf16*)((char*)uA + ((lr*128 + lane*2) ^ ((lr&7)<<4))) = (__bf16)v;
    }
    #pragma unroll
    for (int it=0; it<8; ++it) {
      int g = it*512 + tid;
      int c = g >> 4, q = g & 15;
      float4 w = *(const float4*)(in_w + ((size_t)(i*2*DI) + c)*DM + q*4);
      bf16x4v hv;
      hv[0]=(__bf16)w.x; hv[1]=(__bf16)w.y; hv[2]=(__bf16)w.z; hv[3]=(__bf16)w.w;
      *(bf16x4v*)((char*)uB + ((c*128 + q*8) ^ ((c&7)<<4))) = hv;
    }
  }
  __syncthreads();

  // ---- P2: in_proj via MFMA ----
  const int lane = tid & 63, wv = tid >> 6;
  f32x4 acc[5][2];
  {
    f32x4 z4 = {0.f, 0.f, 0.f, 0.f};
    #pragma unroll
    for (int mt=0; mt<5; ++mt){ acc[mt][0] = z4; acc[mt][1] = z4; }
    bf16x8v bfr[2][2];
    #pragma unroll
    for (int ntl=0; ntl<2; ++ntl)
      #pragma unroll
      for (int kt=0; kt<2; ++kt){
        int c = (wv*2+ntl)*16 + (lane&15);
        int byt = (c*128 + kt*64 + (lane>>4)*16) ^ ((c&7)<<4);
        bfr[ntl][kt] = *(const bf16x8v*)((const char*)uB + byt);
      }
    #pragma unroll
    for (int mt=0; mt<5; ++mt){
      bf16x8v afr[2];
      #pragma unroll
      for (int kt=0; kt<2; ++kt){
        int row = mt*16 + (lane&15);
        int byt = (row*128 + kt*64 + (lane>>4)*16) ^ ((row&7)<<4);
        afr[kt] = *(const bf16x8v*)((const char*)uA + byt);
      }
      #pragma unroll
      for (int ntl=0; ntl<2; ++ntl){
        acc[mt][ntl] = __builtin_amdgcn_mfma_f32_16x16x32_bf16(afr[0], bfr[ntl][0], acc[mt][ntl], 0,0,0);
        acc[mt][ntl] = __builtin_amdgcn_mfma_f32_16x16x32_bf16(afr[1], bfr[ntl][1], acc[mt][ntl], 0,0,0);
      }
    }
  }
  __syncthreads();

  // ---- P3/P4 by 32-row halves: xi-half -> uA, conv -> xc hi/lo in uB ----
  {
    const int d = tid & 127, rh = tid >> 7;
    const float4 cw = *(const float4*)(conv_w + (size_t)(i*DI + d)*KC);
    const float cb = conv_b[i*DI + d];
    #pragma unroll
    for (int h=0; h<2; ++h) {
      if (wv < 4) {
        #pragma unroll
        for (int mt=0; mt<5; ++mt)
          #pragma unroll
          for (int ntl=0; ntl<2; ++ntl)
            #pragma unroll
            for (int r=0; r<4; ++r){
              int m = mt*16 + (lane>>4)*4 + r;
              if (m >= h*32 && m <= h*32+34)
                uA[(m - h*32)*129 + wv*32 + ntl*16 + (lane&15)] = acc[mt][ntl][r];
            }
      } else if (h == 0) {
        // z direct to global (64B chunks per quarter-wave)
        #pragma unroll
        for (int mt=0; mt<5; ++mt)
          #pragma unroll
          for (int ntl=0; ntl<2; ++ntl)
            #pragma unroll
            for (int r=0; r<4; ++r){
              int m = mt*16 + (lane>>4)*4 + r;
              if (m >= 3 && m <= 66)
                zg[(rbase + (m-3))*DI + (wv-4)*32 + ntl*16 + (lane&15)] = acc[mt][ntl][r];
            }
      }
      __syncthreads();
      #pragma unroll
      for (int rr=0; rr<8; ++rr){
        int r = h*32 + rh*8 + rr;
        int lb = rh*8 + rr;
        float v0 = uA[(lb  )*129 + d];
        float v1 = uA[(lb+1)*129 + d];
        float v2 = uA[(lb+2)*129 + d];
        float v3 = uA[(lb+3)*129 + d];
        float aa = cb + cw.x*v0 + cw.y*v1 + cw.z*v2 + cw.w*v3;
        float xc = aa * fsig(aa);
        xcg[(rbase + r)*DI + d] = xc;
        __bf16 hh = (__bf16)xc;
        __bf16 ll = (__bf16)(xc - (float)hh);
        int off = (r*256 + d*2) ^ ((r&7)<<4);
        *(__bf16*)((char*)uB + off) = hh;
        *(__bf16*)((char*)uB + off + 16384) = ll;
      }
      __syncthreads();
    }
  }

  // ---- P5: stage xp_w hi/lo bf16 into uA (xi dead) ----
  for (int e = tid; e < 36*32; e += 512) {
    int j = e >> 5, k0 = (e & 31)*4;
    float4 w = *(const float4*)(xp_w + ((size_t)(i*36) + j)*DI + k0);
    float vv[4] = {w.x, w.y, w.z, w.w};
    bf16x4v hv, lv;
    #pragma unroll
    for (int k=0;k<4;++k){
      __bf16 hh = (__bf16)vv[k];
      hv[k] = hh;
      lv[k] = (__bf16)(vv[k] - (float)hh);
    }
    int off = (j*256 + k0*2) ^ ((j&7)<<4);
    *(bf16x4v*)((char*)uA + off) = hv;
    *(bf16x4v*)((char*)uA + off + 9216) = lv;
  }
  __syncthreads();

  // ---- P6: x_proj split-precision MFMA; dtl->uA@f4608, B->Bg, C->Cg ----
  for (int t = wv; t < 12; t += 8) {
    int mt = t & 3, nt = t >> 2;
    f32x4 a2 = {0.f,0.f,0.f,0.f};
    #pragma unroll
    for (int kt=0; kt<4; ++kt){
      int row = mt*16 + (lane&15);
      int ab = (row*256 + kt*64 + (lane>>4)*16) ^ ((row&7)<<4);
      bf16x8v ah = *(const bf16x8v*)((const char*)uB + ab);
      bf16x8v al = *(const bf16x8v*)((const char*)uB + ab + 16384);
      int col = nt*16 + (lane&15);
      int bby = (col*256 + kt*64 + (lane>>4)*16) ^ ((col&7)<<4);
      bf16x8v bh = *(const bf16x8v*)((const char*)uA + bby);
      bf16x8v bl = *(const bf16x8v*)((const char*)uA + bby + 9216);
      a2 = __builtin_amdgcn_mfma_f32_16x16x32_bf16(ah, bh, a2, 0,0,0);
      a2 = __builtin_amdgcn_mfma_f32_16x16x32_bf16(al, bh, a2, 0,0,0);
      a2 = __builtin_amdgcn_mfma_f32_16x16x32_bf16(ah, bl, a2, 0,0,0);
    }
    #pragma unroll
    for (int rg4=0; rg4<4; ++rg4){
      int row = mt*16 + (lane>>4)*4 + rg4;
      int j = nt*16 + (lane&15);
      float val = a2[rg4];
      if (j < 4) uA[4608 + row*4 + j] = val;
      else if (j < 20) Bg[(rbase+row)*NS + (j-4)] = val;
      else if (j < 36) Cg[(rbase+row)*NS + (j-20)] = val;
    }
  }
  __syncthreads();

  // ---- P7: dt = softplus(dtl @ dtp_w^T + bias), fast log path ----
  #pragma unroll 4
  for (int it=0; it<16; ++it) {
    int e = it*512 + tid;
    int r = e >> 7, d = e & 127;
    float4 dl = *(const float4*)&uA[4608 + r*4];
    float4 w  = *(const float4*)(dtp_w + (size_t)(i*DI + d)*RK);
    float a = dt_b[i*DI + d] + dot4(w, dl);
    dtg[(rbase + r)*DI + d] = (a > 15.f) ? a : __logf(1.f + __expf(a));
  }
}

// ---------------------------------------------------------------------------
// KB v2: pass1 local scan, NO LDS / NO barriers — direct global reads
// ---------------------------------------------------------------------------
__global__ __launch_bounds__(256) void kb_pass1(
    const float* __restrict__ dtg, const float* __restrict__ xcg, const float* __restrict__ Bg,
    const float* __restrict__ A_log,
    float* __restrict__ Pm, float* __restrict__ hend)
{
  const int tid = threadIdx.x;
  const int bx = blockIdx.x;
  const int c = bx % NC; const int i = (bx/NC)&1; const int b = bx/(2*NC);
  const int d = tid >> 1, half = tid & 1, n0 = half*8;
  float a[8], h[8];
  bool afast = true;
  #pragma unroll
  for (int n=0;n<8;++n){
    a[n] = -__expf(A_log[((size_t)(i*DI)+d)*NS + n0+n]);
    float tgt = (float)(n0+n+1);
    afast = afast && (fabsf(a[n] + tgt) <= 1e-4f*tgt);
    h[n] = 0.f;
  }
  float S = 0.f;
  const size_t rb = ((size_t)(b*2+i)*Lx + (size_t)c*CT);
  for (int r4 = 0; r4 < CT; r4 += 4){
    float dt4[4], x4[4];
    #pragma unroll
    for (int k=0;k<4;++k){
      size_t g = (rb + r4 + k)*DI + d;
      dt4[k] = dtg[g];
      x4[k]  = xcg[g];
    }
    #pragma unroll
    for (int k=0;k<4;++k){
      float dtt = dt4[k];
      float u = dtt * x4[k];
      S += dtt;
      const float* bp = &Bg[(rb + r4 + k)*NS + n0];
      float4 b0 = *(const float4*)bp;
      float4 b1 = *(const float4*)(bp+4);
      float bb[8] = {b0.x,b0.y,b0.z,b0.w,b1.x,b1.y,b1.z,b1.w};
      if (afast){
        float rr = __expf(-dtt);
        float dA;
        if (half){ float r2=rr*rr, r4v=r2*r2; dA = r4v*r4v*rr; } else dA = rr;
        h[0] = fmaf(dA, h[0], u*bb[0]);
        #pragma unroll
        for (int n=1;n<8;++n){ dA *= rr; h[n] = fmaf(dA, h[n], u*bb[n]); }
      } else {
        #pragma unroll
        for (int n=0;n<8;++n){
          float dA = __expf(a[n]*dtt);
          h[n] = fmaf(dA, h[n], u*bb[n]);
        }
      }
    }
  }
  size_t ob = (((size_t)(b*2+i)*NC + c)*DI + d)*NS + n0;
  #pragma unroll
  for (int n=0;n<8;++n){
    Pm[ob+n] = __expf(a[n]*S);
    hend[ob+n] = h[n];
  }
}

// ---------------------------------------------------------------------------
// KC: pass2 — propagate chunk boundary states; h0 written IN PLACE over Pm
// ---------------------------------------------------------------------------
__global__ __launch_bounds__(256) void kc_pass2(
    float* __restrict__ Pm, const float* __restrict__ hend)
{
  const int tid = threadIdx.x;
  const int bi = blockIdx.x;
  const int d = tid>>1, n0 = (tid&1)*8;
  float h[8];
  #pragma unroll
  for (int n=0;n<8;++n) h[n]=0.f;
  for (int c=0;c<NC;++c){
    size_t ob = (((size_t)bi*NC + c)*DI + d)*NS + n0;
    float p[8], hev[8];
    #pragma unroll
    for (int n=0;n<8;++n){ p[n]=Pm[ob+n]; hev[n]=hend[ob+n]; }
    #pragma unroll
    for (int n=0;n<8;++n){ Pm[ob+n] = h[n]; h[n] = fmaf(p[n], h[n], hev[n]); }
  }
}

// ---------------------------------------------------------------------------
// KD v2: pass3 scan, NO LDS / NO barriers — direct global reads; y -> dtg.
// ---------------------------------------------------------------------------
__global__ __launch_bounds__(256) void kd_pass3(
    const float* dtg, const float* __restrict__ xcg, const float* __restrict__ Bg,
    const float* __restrict__ Cg, const float* __restrict__ A_log, const float* __restrict__ Dp,
    const float* __restrict__ h0, const float* __restrict__ zg, float* yout)
{
  const int tid = threadIdx.x;
  const int bx = blockIdx.x;
  const int c = bx % NC; const int i = (bx/NC)&1; const int b = bx/(2*NC);
  const int d = tid >> 1, half = tid & 1, n0 = half*8;
  float a[8], h[8];
  bool afast = true;
  size_t hb = (((size_t)(b*2+i)*NC + c)*DI + d)*NS + n0;
  #pragma unroll
  for (int n=0;n<8;++n){
    a[n] = -__expf(A_log[((size_t)(i*DI)+d)*NS + n0+n]);
    float tgt = (float)(n0+n+1);
    afast = afast && (fabsf(a[n] + tgt) <= 1e-4f*tgt);
    h[n] = h0[hb+n];
  }
  const float Dd = Dp[i*DI + d];
  const size_t rb = ((size_t)(b*2+i)*Lx + (size_t)c*CT);
  for (int r4 = 0; r4 < CT; r4 += 4){
    float dt4[4], x4[4], z4[4];
    #pragma unroll
    for (int k=0;k<4;++k){
      size_t g = (rb + r4 + k)*DI + d;
      dt4[k] = dtg[g];
      x4[k]  = xcg[g];
      z4[k]  = zg[g];
    }
    #pragma unroll
    for (int k=0;k<4;++k){
      float dtt = dt4[k];
      float xcv = x4[k];
      float u = dtt * xcv;
      const float* bp = &Bg[(rb + r4 + k)*NS + n0];
      const float* cp = &Cg[(rb + r4 + k)*NS + n0];
      float4 b0 = *(const float4*)bp;
      float4 b1 = *(const float4*)(bp+4);
      float4 c0 = *(const float4*)cp;
      float4 c1 = *(const float4*)(cp+4);
      float bb[8] = {b0.x,b0.y,b0.z,b0.w,b1.x,b1.y,b1.z,b1.w};
      float cc[8] = {c0.x,c0.y,c0.z,c0.w,c1.x,c1.y,c1.z,c1.w};
      float part = 0.f;
      if (afast){
        float rr = __expf(-dtt);
        float dA;
        if (half){ float r2=rr*rr, r4v=r2*r2; dA = r4v*r4v*rr; } else dA = rr;
        h[0] = fmaf(dA, h[0], u*bb[0]);
        part = fmaf(h[0], cc[0], part);
        #pragma unroll
        for (int n=1;n<8;++n){
          dA *= rr;
          h[n] = fmaf(dA, h[n], u*bb[n]);
          part = fmaf(h[n], cc[n], part);
        }
      } else {
        #pragma unroll
        for (int n=0;n<8;++n){
          float dA = __expf(a[n]*dtt);
          h[n] = fmaf(dA, h[n], u*bb[n]);
          part = fmaf(h[n], cc[n], part);
        }
      }
      float y = part + __shfl_xor(part, 1);
      if (half == 0){
        float zz = z4[k];
        yout[(rb + r4 + k)*DI + d] = fmaf(xcv, Dd, y) * (zz * fsig(zz));
      }
    }
  }
}

// ---------------------------------------------------------------------------
// KE v2: out-proj via bf16 MFMA (coalesced LDS staging, swz)
// ---------------------------------------------------------------------------
__global__ __launch_bounds__(256) void ke_out(
    const float* __restrict__ yg, const float* __restrict__ ow, float* __restrict__ out)
{
  __shared__ char sY[16384];   // [32 rows][256 k] bf16, swz
  __shared__ char sW[32768];   // [64 ch ][256 k] bf16, swz
  const int tid = threadIdx.x;
  const int bx = blockIdx.x;
  const int tile = bx & 127; const int b = bx >> 7;
  const int l0 = tile * 32;
  #pragma unroll
  for (int it=0; it<16; ++it){
    int e = it*256 + tid;
    int dir = e >> 11, c = (e >> 5) & 63, q = e & 31;
    float4 w = *(const float4*)(ow + ((size_t)(dir*DM + c))*DI + q*4);
    bf16x4v hv; hv[0]=(__bf16)w.x; hv[1]=(__bf16)w.y; hv[2]=(__bf16)w.z; hv[3]=(__bf16)w.w;
    *(bf16x4v*)(sW + ((c*512 + dir*256 + q*8) ^ ((c&7)<<4))) = hv;
  }
  #pragma unroll
  for (int it=0; it<8; ++it){
    int e = it*256 + tid;
    int dir = e >> 10, r = (e >> 5) & 31, q = e & 31;
    size_t row = dir ? ((size_t)(b*2+1)*Lx + (size_t)(Lx-1-(l0+r)))
                     : ((size_t)(b*2  )*Lx + (size_t)(l0+r));
    float4 v = *(const float4*)(yg + row*DI + q*4);
    bf16x4v hv; hv[0]=(__bf16)v.x; hv[1]=(__bf16)v.y; hv[2]=(__bf16)v.z; hv[3]=(__bf16)v.w;
    *(bf16x4v*)(sY + ((r*512 + dir*256 + q*8) ^ ((r&7)<<4))) = hv;
  }
  __syncthreads();
  const int lane = tid & 63, wv = tid >> 6;
  #pragma unroll
  for (int t=0; t<2; ++t){
    int T = wv*2 + t, mt = T >> 2, nt = T & 3;
    f32x4 acc = {0.f,0.f,0.f,0.f};
    #pragma unroll
    for (int kt=0; kt<8; ++kt){
      int row = mt*16 + (lane&15);
      bf16x8v av = *(const bf16x8v*)(sY + ((row*512 + kt*64 + (lane>>4)*16) ^ ((row&7)<<4)));
      int ch = nt*16 + (lane&15);
      bf16x8v wvv = *(const bf16x8v*)(sW + ((ch*512 + kt*64 + (lane>>4)*16) ^ ((ch&7)<<4)));
      acc = __builtin_amdgcn_mfma_f32_16x16x32_bf16(av, wvv, acc, 0,0,0);
    }
    #pragma unroll
    for (int r=0; r<4; ++r){
      int m = mt*16 + (lane>>4)*4 + r;
      int ch = nt*16 + (lane&15);
      out[((size_t)b*Lx + (size_t)(l0+m))*DM + ch] = acc[r];
    }
  }
}

extern "C" void kernel_launch(void* const* d_in, const int* in_sizes, int n_in,
                              void* d_out, int out_size, void* d_ws, size_t ws_size,
                              hipStream_t stream)
{
  const float* x      = (const float*)d_in[0];
  const float* ln_g   = (const float*)d_in[1];
  const float* ln_b   = (const float*)d_in[2];
  const float* in_w   = (const float*)d_in[3];
  const float* conv_w = (const float*)d_in[4];
  const float* conv_b = (const float*)d_in[5];
  const float* xp_w   = (const float*)d_in[6];
  const float* dtp_w  = (const float*)d_in[7];
  const float* dt_b   = (const float*)d_in[8];
  const float* A_log  = (const float*)d_in[9];
  const float* Dp     = (const float*)d_in[10];
  const float* ow     = (const float*)d_in[11];
  float* out = (float*)d_out;
  float* ws = (float*)d_ws;
  const size_t NBD = (size_t)Bsz*2*Lx*DI;     // 8,388,608
  const size_t NBN = (size_t)Bsz*2*Lx*NS;     // 1,048,576
  float* xcg = ws;
  float* dtg = xcg + NBD;
  float* zg  = dtg + NBD;
  float* Bg  = zg + NBD;
  float* Cg  = Bg + NBN;
  float* Pm  = Cg + NBN;          // becomes h0 in-place after kc
  float* he  = out;               // hend staged in d_out (fully overwritten by ke)

  a1_front<<<dim3(Bsz*2*(Lx/64)), dim3(512), 0, stream>>>(
      x, ln_g, ln_b, in_w, conv_w, conv_b, xp_w, dtp_w, dt_b, xcg, dtg, zg, Bg, Cg);
  kb_pass1<<<dim3(Bsz*2*NC), dim3(256), 0, stream>>>(dtg, xcg, Bg, A_log, Pm, he);
  kc_pass2<<<dim3(Bsz*2), dim3(256), 0, stream>>>(Pm, he);
  kd_pass3<<<dim3(Bsz*2*NC), dim3(256), 0, stream>>>(dtg, xcg, Bg, Cg, A_log, Dp, Pm, zg, dtg);
  ke_out<<<dim3(Bsz*(Lx/32)), dim3(256), 0, stream>>>(dtg, ow, out);
}